// Round 6
// baseline (403.623 us; speedup 1.0000x reference)
//
#include <hip/hip_runtime.h>
#include <math.h>

#define NTH 256

// packed complex: x=re, y=im. ext_vector arithmetic lowers to <2 x float> IR ->
// VOP3P v_pk_{add,mul,fma}_f32 on gfx950 (packed dual-FP32). Worst case it
// scalarizes to exactly the scalar code we had — no regression path.
typedef __attribute__((ext_vector_type(2))) float v2f;

// z * (c + i s): 1 pk_mul + 1 pk_mul + 1 pk_add (contract -> pk_fma)
__device__ __forceinline__ v2f cmulv(v2f z, float c, float s) {
    v2f t; t.x = -z.y; t.y = z.x;       // i*z
    return z * c + t * s;
}

// in-place FFT-4 on v2f, natural order, W4 = -i (8 packed adds)
#define FFT4V(z0,z1,z2,z3) {                      \
    v2f _ac = (z0) + (z2), _sc = (z0) - (z2);     \
    v2f _bd = (z1) + (z3), _sd = (z1) - (z3);     \
    v2f _jd; _jd.x = _sd.y; _jd.y = -_sd.x;       \
    (z0) = _ac + _bd;                             \
    (z1) = _sc + _jd;                             \
    (z2) = _ac - _bd;                             \
    (z3) = _sc - _jd; }

// FFT-16, natural input. OUTPUT DIGIT-SWAPPED: slot (4s+g) holds Y[s+4g].
__device__ __forceinline__ void fft16v(v2f* z) {
    const float C1 = 0.92387953251128675613f;   // cos(pi/8)
    const float S1 = 0.38268343236508977172f;   // sin(pi/8)
    const float R2 = 0.70710678118654752440f;
#pragma unroll
    for (int q = 0; q < 4; ++q) FFT4V(z[q], z[4+q], z[8+q], z[12+q]);
    z[5]  = cmulv(z[5],   C1, -S1);                       // W^1
    z[9]  = cmulv(z[9],   R2, -R2);                       // W^2
    z[13] = cmulv(z[13],  S1, -C1);                       // W^3
    z[6]  = cmulv(z[6],   R2, -R2);                       // W^2
    { v2f t; t.x = z[10].y; t.y = -z[10].x; z[10] = t; }  // W^4 = -i
    z[14] = cmulv(z[14], -R2, -R2);                       // W^6
    z[7]  = cmulv(z[7],   S1, -C1);                       // W^3
    z[11] = cmulv(z[11], -R2, -R2);                       // W^6
    z[15] = cmulv(z[15], -C1,  S1);                       // W^9
#pragma unroll
    for (int s = 0; s < 4; ++s) FFT4V(z[4*s], z[4*s+1], z[4*s+2], z[4*s+3]);
}

// One WAVE per row (4 rows / 256-thread block). T=2048. No __syncthreads:
// all LDS hazards are same-wave (DS ops execute in issue order per wave).
//
// LDS: one v2f[1024] per wave (32 KiB/block total, same as before) -> every
// complex access is ONE ds_read_b64/ds_write_b64 (DS op count halved vs the
// split-Zr/Zi float layout). Swizzle unchanged: complex index e lives at slot
// e ^ (e>>6) in phase 1/2; final (post-C3) layout is IDENTITY.
//
// VGPR history (measured): (256,5)->48 VGPR, ~60 dwords/thread spilled;
// (256,4)->64 VGPR, 7 dwords spilled (WRITE 58.6MB); (256,2)->64 VGPR, zero
// spill, VALUBusy 97%. Keep (256,2): occupancy is LDS-capped, the relaxed
// VGPR cap costs nothing, and v2f pairing needs the headroom.
__global__ __launch_bounds__(NTH, 2)
void feat_kernel(const float* __restrict__ gx, float* __restrict__ gout) {
    const int tid = threadIdx.x;
    const int wv  = tid >> 6;
    const int ln  = tid & 63;
    const int row = blockIdx.x * 4 + wv;
    const float* xrow = gx + (size_t)row * 2048;
    float* orow = gout + (size_t)row * 10;

    __shared__ v2f Zs_[4][1024];
    v2f* Zs = Zs_[wv];

    const int al  = ln & 3;
    const int k2r = ln >> 2;          // == swizzle key (e>>6) for the 16-stride patterns
    const int b5  = ln >> 5;

    // ---- coalesced load; pack z[n]=x[2n]+i*x[2n+1] at swizzled slots ----
    const float4* x4 = (const float4*)xrow;
#pragma unroll
    for (int t = 0; t < 8; ++t) {
        float4 u = x4[ln + 64 * t];
        int c  = 2 * ln + 128 * t;            // even complex index
        int a0 = c ^ (2 * t + b5);            // SW(c): (c>>6) = 2t + b5 <= 15
        int a1 = a0 ^ 1;                      // SW(c+1)
        v2f w0; w0.x = u.x; w0.y = u.y;
        v2f w1; w1.x = u.z; w1.y = u.w;
        Zs[a0] = w0;
        Zs[a1] = w1;
    }

    // ---- contiguous 32 samples into regs: complex j of lane = s[32ln+2j(+1)] ----
    v2f r2[16];
    {
        int base = 16 * ln;
#pragma unroll
        for (int j = 0; j < 16; ++j)
            r2[j] = Zs[base + (j ^ k2r)];     // SW(16ln+j): XOR hits low4 (=j)
    }

    // ---- fused elementwise pass: max / min / sum / sum-of-squares (packed) ----
    v2f mx2 = r2[0], mn2 = r2[0], sm2 = r2[0], sq2 = r2[0] * r2[0];
#pragma unroll
    for (int j = 1; j < 16; ++j) {
        v2f e = r2[j];
        mx2.x = fmaxf(mx2.x, e.x); mx2.y = fmaxf(mx2.y, e.y);
        mn2.x = fminf(mn2.x, e.x); mn2.y = fminf(mn2.y, e.y);
        sm2 += e;
        sq2 = e * e + sq2;                    // pk_fma
    }
    float vmax = fmaxf(mx2.x, mx2.y), vmin = fminf(mn2.x, mn2.y);
    float vsum = sm2.x + sm2.y, vsq = sq2.x + sq2.y;
#pragma unroll
    for (int o = 1; o < 64; o <<= 1) {
        vmax = fmaxf(vmax, __shfl_xor(vmax, o, 64));
        vmin = fminf(vmin, __shfl_xor(vmin, o, 64));
        vsum += __shfl_xor(vsum, o, 64);
        vsq  += __shfl_xor(vsq,  o, 64);
    }
    {
        float mean = vsum * (1.0f / 2048.0f);
        float var = (vsq - vsum * mean) * (1.0f / 2047.0f);
        // EARLY STORE of stats: kills 4 live regs across the FFT section
        if (ln == 0) {
            orow[0] = vmax;
            orow[1] = vmax - vmin;
            orow[2] = var;
            orow[3] = sqrtf(var);
        }
    }

    // ---- peaks / valleys via compare bitwords (tie-exact, 2 cmps/elem) ----
    float lN = __shfl_up(r2[15].y, 1, 64);  // lane-1's last elem (lane0: garbage, masked)
    unsigned aw = 0, bw = 0;                // bit m: a_i = s[i-1]<s[i], b_i = s[i-1]>s[i]
#pragma unroll
    for (int j = 0; j < 16; ++j) {
        float pv = (j == 0) ? lN : r2[j - 1].y;
        float e0 = r2[j].x, e1 = r2[j].y;
        aw |= (unsigned)(pv < e0) << (2 * j);
        bw |= (unsigned)(pv > e0) << (2 * j);
        aw |= (unsigned)(e0 < e1) << (2 * j + 1);
        bw |= (unsigned)(e0 > e1) << (2 * j + 1);
    }
    unsigned an = __shfl_down(aw, 1, 64) & 1u;   // next lane's a at i=32ln+32
    unsigned bn = __shfl_down(bw, 1, 64) & 1u;
    unsigned pm = aw & ((bw >> 1) | (bn << 31)); // peak:   a_i & b_{i+1}
    unsigned vm = bw & ((aw >> 1) | (an << 31)); // valley: b_i & a_{i+1}
    if (ln == 0)  { pm &= ~1u; vm &= ~1u; }                  // exclude i=0
    if (ln == 63) { pm &= 0x7FFFFFFFu; vm &= 0x7FFFFFFFu; }  // exclude i=2047

    int pk = __popc(pm) | (__popc(vm) << 12);    // packed counts (each <= 2047 < 4096)
    int mp = pm ? 32 * ln + __ffs(pm) - 1 : (1 << 30);
    int mv = vm ? 32 * ln + __ffs(vm) - 1 : (1 << 30);
    int Mv = vm ? 32 * ln + 31 - __clz(vm) : -1;
#pragma unroll
    for (int o = 1; o < 64; o <<= 1) {
        pk += __shfl_xor(pk, o, 64);
        mp = min(mp, __shfl_xor(mp, o, 64));
        mv = min(mv, __shfl_xor(mv, o, 64));
        Mv = max(Mv, __shfl_xor(Mv, o, 64));
    }
    const int n_peaks = pk & 0xFFF, n_vals = pk >> 12, p0 = mp, v0 = mv, vlast = Mv;

    {
        float PA = 0.0f, A2f = 0.0f, PH = 0.0f, A1f = 0.0f, PW = 0.0f;
        if (n_peaks >= 1 && n_vals >= 2) {     // wave-uniform
            // v1 = first valley strictly after v0
            int lo = v0 - 32 * ln;
            unsigned sel = (lo < 0) ? 0xFFFFFFFFu : ((lo >= 31) ? 0u : (0xFFFFFFFFu << (lo + 1)));
            unsigned m2 = vm & sel;
            int mv2 = m2 ? 32 * ln + __ffs(m2) - 1 : (1 << 30);
#pragma unroll
            for (int o = 1; o < 64; o <<= 1) mv2 = min(mv2, __shfl_xor(mv2, o, 64));
            const int v1 = mv2;

            // uniform broadcast reads from phase-1 layout
            auto sAt = [&](int p) -> float {
                int e = p >> 1;
                v2f zz = Zs[e ^ (e >> 6)];
                return (p & 1) ? zz.y : zz.x;
            };
            float s_v0  = sAt(v0), s_p0 = sAt(p0);
            float s_pm1 = sAt(p0 - 1), s_v1m1 = sAt(v1 - 1), s_vLm1 = sAt(vlast - 1);
            PH = s_p0 - s_v0;
            float half = 0.5f * (s_p0 + s_v0);

            // telescoped trapz: trapz(a,b) = Sum_{i in [a,b-1]} s_i - 0.5*(s_a + s_{b-1})
            float S1 = 0.0f, S2 = 0.0f, S3 = 0.0f;
            int li = 1 << 30, ri = -1;
#pragma unroll
            for (int j = 0; j < 16; ++j) {
#pragma unroll
                for (int h = 0; h < 2; ++h) {
                    int i = 32 * ln + 2 * j + h;
                    float si = h ? r2[j].y : r2[j].x;
                    bool geV0 = (i >= v0), geP0 = (i >= p0);
                    if (geV0 && !geP0)  S1 += si;            // [v0, p0-1]
                    if (geP0 && i < v1) S2 += si;            // [p0, v1-1]
                    if (geV0 && i < vlast) S3 += si;         // [v0, vlast-1]
                    if (si >= half) {
                        if (geV0 && !geP0)     li = min(li, i);
                        if (i > v0 && i <= p0) ri = max(ri, i);
                    }
                }
            }
#pragma unroll
            for (int o = 1; o < 64; o <<= 1) {
                S1 += __shfl_xor(S1, o, 64);
                S2 += __shfl_xor(S2, o, 64);
                S3 += __shfl_xor(S3, o, 64);
                li = min(li, __shfl_xor(li, o, 64));
                ri = max(ri, __shfl_xor(ri, o, 64));
            }
            PA  = (S3 - 0.5f * (s_v0 + s_vLm1)) * (1.0f / 30.0f);
            // guards reproduce reference's empty-range -> 0 (possible with tie plateaus)
            A2f = (v1 > p0) ? (S2 - 0.5f * (s_p0 + s_v1m1)) * (1.0f / 30.0f) : 0.0f;
            A1f = (p0 > v0) ? (S1 - 0.5f * (s_v0 + s_pm1)) * (1.0f / 30.0f) : 0.0f;
            if (li == (1 << 30)) li = v0;
            if (ri < 0)          ri = p0;
            PW = (float)(ri - li) * (1.0f / 30.0f);
        }
        // EARLY STORE of ippg block (zeros when guard fails — matches reference)
        if (ln == 0) {
            orow[5] = PA;
            orow[6] = A2f;
            orow[7] = PH;
            orow[8] = A1f;
            orow[9] = PW;
        }
    }

    // ================= FFT-1024: Z[k2+16k1] via 16 x (16 x 4) =================
    // One sincos seeds ALL twiddle ladders (W2048^ln); the rest is packed rotations.
    float s0, c0;
    __sincosf((float)ln * (-3.14159265358979323846f / 1024.0f), &s0, &c0);

    // step A: per-lane FFT-16 over n2 of z[ln + 64*n2]
    v2f az[16];
#pragma unroll
    for (int n2 = 0; n2 < 16; ++n2)
        az[n2] = Zs[(ln ^ n2) + 64 * n2];     // SW(ln + 64*n2)
    fft16v(az);
    // step B: slot idx holds k2=(idx>>2)+4(idx&3); *= W1024^(ln*k2) via complex
    // recurrence with step W1024^ln = (W2048^ln)^2; write slot L=16ln+k2 at SW(L).
    {
        const float cb = c0 * c0 - s0 * s0;
        const float sb = 2.0f * c0 * s0;
        int wb = 16 * ln;
        Zs[wb + k2r] = az[0];                 // k2=0: addr = wb + (0^k2r)
        v2f w; w.x = cb; w.y = sb;
#pragma unroll
        for (int k2 = 1; k2 < 16; ++k2) {
            const int idx = (k2 >> 2) + 4 * (k2 & 3);
            az[idx] = cmulv(az[idx], w.x, w.y);
            Zs[wb + (k2 ^ k2r)] = az[idx];
            w = cmulv(w, cb, sb);             // advance to W1024^(ln*(k2+1))
        }
    }
    // step C: lane' = al + 4*k2r gathers slots L = 16al + k2r + 64b at SW(L)
    {
        int cbase = 16 * al;
#pragma unroll
        for (int b = 0; b < 16; ++b)
            az[b] = Zs[cbase + (k2r ^ b) + 64 * b];
    }
    fft16v(az);                               // slot 4s+g holds u[j], j = s+4g
    // C2: *= W64^(al*j) via complex recurrence; step W64^al from 4 constant pairs
    {
        float cA = (al & 1) ? 0.99518472667219688624f : 1.0f;
        float sA = (al & 1) ? -0.09801714032956060199f : 0.0f;
        float cB = (al & 1) ? 0.95694033573220886494f : 0.98078528040323044913f;
        float sB = (al & 1) ? -0.29028467725446236764f : -0.19509032201612826785f;
        float c1 = (al & 2) ? cB : cA;
        float s1 = (al & 2) ? sB : sA;
        v2f w; w.x = c1; w.y = s1;
#pragma unroll
        for (int j = 1; j < 16; ++j) {
            const int idx = (j >> 2) + 4 * (j & 3);
            az[idx] = cmulv(az[idx], w.x, w.y);
            w = cmulv(w, c1, s1);
        }
    }
    // C3: FFT-4 over alpha (cross-lane); FINAL LAYOUT IDENTITY: Z[K] at addr K,
    // K = k2r + 16*j + 256*g
    {
        const bool hi = (al & 2) != 0;
        const bool b0 = (al & 1) != 0;
        const int g = ((al & 1) << 1) | (al >> 1);
        int fbase = k2r + 256 * g;
#pragma unroll
        for (int idx = 0; idx < 16; ++idx) {
            int j = (idx >> 2) + 4 * (idx & 3);
            float arx = az[idx].x, aix = az[idx].y;
            float tr = __shfl_xor(arx, 2, 64);
            float ti = __shfl_xor(aix, 2, 64);
            float vr = hi ? (tr - arx) : (arx + tr);
            float vi = hi ? (ti - aix) : (aix + ti);
            float sr = __shfl_xor(vr, 1, 64);
            float si = __shfl_xor(vi, 1, 64);
            float Xr, Xi;
            if (!b0) { Xr = hi ? (vr + si) : (vr + sr); Xi = hi ? (vi - sr) : (vi + si); }
            else     { Xr = hi ? (sr - vi) : (sr - vr); Xi = hi ? (si + vr) : (si - vi); }
            v2f X; X.x = Xr; X.y = Xi;
            Zs[fbase + 16 * j] = X;
        }
    }

    // ---- real-split: sum |X[k]| over all 2048 bins; k=0..511 in loop (w=2 flat),
    //      k=0 overweight and k=512 fixed by exact lane-0 correction ----
    float amp = 0.0f;
    {
        v2f rw; rw.x = c0; rw.y = s0;         // W2048^k at k = ln
        const float C16 = 0.98078528040323044913f, S16 = 0.19509032201612826785f;
#pragma unroll
        for (int t = 0; t < 8; ++t) {
            int k = ln + 64 * t;
            int m = (1024 - k) & 1023;
            v2f z  = Zs[k];                   // identity layout
            v2f mz = Zs[m];
            v2f cjm; cjm.x = mz.x; cjm.y = -mz.y;        // conj(mz)
            v2f E = (z + cjm) * 0.5f;
            v2f d = cjm - z;                  // (mr-zr, -mi-zi)
            v2f O; O.x = -0.5f * d.y; O.y = 0.5f * d.x;  // (.5(zi+mi), .5(mr-zr))
            v2f P = cmulv(O, rw.x, rw.y);
            v2f x1 = E + P, x2 = E - P;
            v2f d1 = x1 * x1, d2 = x2 * x2;
            amp += 2.0f * (__builtin_amdgcn_sqrtf(d1.x + d1.y) +
                           __builtin_amdgcn_sqrtf(d2.x + d2.y));
            rw = cmulv(rw, C16, -S16);        // rotate by W2048^64 = e^{-i*pi/16}
        }
        {
            v2f z0v = Zs[0];
            float q1 = z0v.x + z0v.y, q2 = z0v.x - z0v.y;
            // loop's k=0 term was exactly 2*(sqrt(q1^2)+sqrt(q2^2)); want weight 1
            float corr0 = __builtin_amdgcn_sqrtf(q1 * q1) + __builtin_amdgcn_sqrtf(q2 * q2);
            v2f z5 = Zs[512];
            float c512 = 2.0f * __builtin_amdgcn_sqrtf(z5.x * z5.x + z5.y * z5.y);
            amp += (ln == 0) ? (c512 - corr0) : 0.0f;
        }
    }
#pragma unroll
    for (int o = 1; o < 64; o <<= 1) amp += __shfl_xor(amp, o, 64);

    if (ln == 0) {
        orow[4] = amp * (1.0f / 2048.0f);
    }
}

extern "C" void kernel_launch(void* const* d_in, const int* in_sizes, int n_in,
                              void* d_out, int out_size, void* d_ws, size_t ws_size,
                              hipStream_t stream) {
    (void)d_ws; (void)ws_size; (void)n_in; (void)out_size;
    const float* x = (const float*)d_in[0];
    float* out = (float*)d_out;
    int rows = in_sizes[0] / 2048;           // 32768
    feat_kernel<<<dim3(rows / 4), dim3(NTH), 0, stream>>>(x, out);
}